// Round 1
// 1120.093 us; speedup vs baseline: 1.1415x; 1.1415x over previous
//
#include <hip/hip_runtime.h>
#include <cstdint>
#include <cstddef>

// ---------------------------------------------------------------------------
// GateLoop block, round 6: mgemm pipeline rework.
//   (a) XCD-chunked block swizzle (T1): 8 blocks sharing an A row-panel were
//       round-robined onto 8 different XCD L2s -> 4.3x A over-fetch on the
//       W2 GEMM (FETCH 591MB vs 137 ideal). Chunked swizzle makes A panels
//       XCD-private.
//   (b) Double-buffered LDS, single barrier per K-step: stage(t+1) issued
//       after the barrier, before compute(t) -> global-load latency hides
//       under the previous tile's MFMA phase (old code fully drained vmcnt
//       between stage and compute every step).
//   (c) LDS chunk-XOR swizzle: [row][32f16] rows are 64B -> fragment
//       ds_read_b128 hit only banks {0-3,16-19} (SQ_LDS_BANK_CONFLICT
//       1.7e7 ~ 10%). XOR the 16B chunk index with (row>>1)&3, applied on
//       BOTH the pre-swizzled global source (global_load_lds writes
//       linearly) and the ds_read offset. -> 2-way (free).
//
// Pipeline (unchanged):
//   0. x -> fp16; weights -> transposed fp16 [N,K]
//   1. mgemm x@{Wq,Wk,Wv,Wa,Wg}; v fused *k -> kv; g fused silu (fp16 out)
//   2. a_transform in place (fp16, lives in d_out)
//   3. chunked scan (3 passes, fp32 state); Im(y) only as GN stats (atomics)
//   4. gn_gate (fp16); 5. mgemm y@Wo -> yo; ln1 -> x1 (fp16)
//   6. mgemm x1@W1(+b1,gelu) -> h1 ; mgemm h1@W2(+b2) -> h2 (fp32, d_out)
//   7. ln2(x1 + h2) -> out (in place over h2, per-thread read-then-write)
//
// ws layout (MiB): 0 W1T(8) | 8 W2T(8) | 16 WqT | 18 WkT | 20 WvT | 22 WgT |
//   24 WoT | 26 WaT(4) | 30 chunk(4) | 34 carry(2) | 36 stats | 37 xb(32) |
//   69 kvb | 101 qb | 133 gb | 165 yb | 197 end.  (197 MiB proven safe r2)
// Aliases: yo->qb, x1->xb, h1(128 MiB)->69..197, a & h2 -> d_out.
// ---------------------------------------------------------------------------

#define EPSN 1e-6f

typedef _Float16 f16;
typedef _Float16 f16x8 __attribute__((ext_vector_type(8)));
typedef _Float16 f16x4 __attribute__((ext_vector_type(4)));
typedef float    f32x4 __attribute__((ext_vector_type(4)));

static constexpr int    Bb     = 4;
static constexpr int    Ss     = 4096;
static constexpr int    Dd     = 1024;
static constexpr int    Ff     = 4096;
static constexpr int    Mrows  = Bb * Ss;                  // 16384
static constexpr size_t MD     = (size_t)Mrows * Dd;       // 16777216
static constexpr int    CHUNKS = 64;
static constexpr int    CLEN   = Ss / CHUNKS;              // 64
static constexpr int    BD     = Bb * Dd;                  // 4096
static constexpr int    CBD    = CHUNKS * BD;              // 262144
static constexpr size_t MiB    = 1024 * 1024;

__device__ __forceinline__ float gelu_tanh(float x) {
    float x3 = x * x * x;
    float t  = tanhf(0.7978845608028654f * (x + 0.044715f * x3));
    return 0.5f * x * (1.0f + t);
}
__device__ __forceinline__ float silu(float x) { return x / (1.0f + expf(-x)); }

// async global->LDS, 16 B per lane; lds dest = base + lane*16 (wave-uniform base)
__device__ __forceinline__ void async16(const void* g, void* l) {
    __builtin_amdgcn_global_load_lds(
        (const __attribute__((address_space(1))) unsigned int*)(uintptr_t)g,
        (__attribute__((address_space(3))) unsigned int*)(uintptr_t)l,
        16, 0, 0);
}

// ---------------- MFMA GEMM: C[M,N] = A[M,K](f16) @ Bt[N,K](f16)^T ----------
// EPI: 0 none | 1 bias+gelu | 2 bias | 3 mul-by-existing-C(f16) | 4 silu
//
// LDS tile layout: [row][4 chunks of 8 f16], chunk index XOR'd with
// (row>>1)&3 for bank spread. K%64 == 0 assumed (K is 1024 or 4096).
template <int EPI, typename TC>
__global__ __launch_bounds__(256) void mgemm_k(const f16* __restrict__ A,
                                               const f16* __restrict__ Bt,
                                               TC* __restrict__ C,
                                               int M, int N, int K,
                                               const float* __restrict__ bias) {
    __shared__ f16 As[2][128 * 32];
    __shared__ f16 Bs[2][128 * 32];
    const int tid  = threadIdx.x;
    const int wave = tid >> 6;
    const int lane = tid & 63;

    // XCD-chunked bijective swizzle (all grids have nwg % 8 == 0)
    const int gx  = gridDim.x;
    const int nwg = gx * gridDim.y;
    int bid = blockIdx.y * gx + blockIdx.x;
    bid = (bid & 7) * (nwg >> 3) + (bid >> 3);
    const int bm = (bid / gx) * 128;
    const int bn = (bid % gx) * 128;

    const int rw = (wave & 1) * 64;
    const int cw = (wave >> 1) * 64;

    // staging: lane l owns LDS (row = l>>2, chunk = l&3); it must fetch
    // global chunk c = (l&3) ^ f(row), f(row) = (row>>1)&3 = (l>>3)&3
    const int swzc = (((lane & 3) ^ (lane >> 3)) & 3) * 8;
    const f16* gA = A  + (size_t)(bm + wave * 32 + (lane >> 2)) * K + swzc;
    const f16* gB = Bt + (size_t)(bn + wave * 32 + (lane >> 2)) * K + swzc;
    f16* const lA0 = &As[0][wave * 1024];
    f16* const lA1 = &As[1][wave * 1024];
    f16* const lB0 = &Bs[0][wave * 1024];
    f16* const lB1 = &Bs[1][wave * 1024];

    f32x4 acc[4][4] = {};

    // fragment read: want global chunk g=(lane>>4) at row (..+fr);
    // stored at LDS chunk g ^ ((fr>>1)&3)   (fr bits 1-2 == lane bits 1-2)
    const int fr  = lane & 15;
    const int fco = (((lane >> 4) ^ (lane >> 1)) & 3) * 8;

#define MG_STAGE(KOFF, LA, LB)                                     \
    {                                                              \
        async16(gA + (KOFF),                   (LA));              \
        async16(gA + 16 * (size_t)K + (KOFF),  (LA) + 512);        \
        async16(gB + (KOFF),                   (LB));              \
        async16(gB + 16 * (size_t)K + (KOFF),  (LB) + 512);        \
    }

#define MG_COMPUTE(LSA, LSB)                                                   \
    {                                                                          \
        f16x8 af[4], bfr[4];                                                   \
        _Pragma("unroll") for (int i = 0; i < 4; ++i)                          \
            af[i] = *(const f16x8*)&(LSA)[(rw + i * 16 + fr) * 32 + fco];      \
        _Pragma("unroll") for (int j = 0; j < 4; ++j)                          \
            bfr[j] = *(const f16x8*)&(LSB)[(cw + j * 16 + fr) * 32 + fco];     \
        _Pragma("unroll") for (int i = 0; i < 4; ++i)                          \
            _Pragma("unroll") for (int j = 0; j < 4; ++j)                      \
                acc[i][j] = __builtin_amdgcn_mfma_f32_16x16x32_f16(           \
                    af[i], bfr[j], acc[i][j], 0, 0, 0);                        \
    }

    // pipeline: one __syncthreads per K-step. At the barrier, the only
    // outstanding loads are the current tile's (issued one compute-phase
    // ago) -> the implicit vmcnt(0) drain is cheap. stage(t+1) is issued
    // after the barrier (all waves done reading buf^1) and lands during
    // compute(t), which only reads buf.
    MG_STAGE(0, lA0, lB0);
    for (int k0 = 0; k0 < K; k0 += 64) {
        __syncthreads();
        MG_STAGE(k0 + 32, lA1, lB1);
        MG_COMPUTE(As[0], Bs[0]);
        __syncthreads();
        if (k0 + 64 < K) MG_STAGE(k0 + 64, lA0, lB0);
        MG_COMPUTE(As[1], Bs[1]);
    }
#undef MG_STAGE
#undef MG_COMPUTE

    // epilogue: C row = (lane>>4)*4 + reg, col = lane&15  (dtype-independent)
    const int er = (lane >> 4) * 4;
    const int ec = lane & 15;
#pragma unroll
    for (int i = 0; i < 4; ++i) {
#pragma unroll
        for (int j = 0; j < 4; ++j) {
            const int col = bn + cw + j * 16 + ec;
#pragma unroll
            for (int r = 0; r < 4; ++r) {
                const size_t row = (size_t)(bm + rw + i * 16 + er + r);
                float o = acc[i][j][r];
                if (EPI == 1 || EPI == 2) o += bias[col];
                if (EPI == 1) o = gelu_tanh(o);
                if (EPI == 4) o = silu(o);
                if (EPI == 3) o *= (float)((const f16*)C)[row * N + col];
                if (sizeof(TC) == 4) ((float*)C)[row * N + col] = o;
                else                 ((f16*)C)[row * N + col] = (f16)o;
            }
        }
    }
}

// ---------------- weight transpose+convert: Wt[n][k] = f16(W[k][n]) ---------
__global__ __launch_bounds__(256) void wtrans_k(const float* __restrict__ W,
                                                f16* __restrict__ Wt,
                                                int K, int N) {
    __shared__ float t[32][33];
    const int n0 = blockIdx.x * 32, k0 = blockIdx.y * 32;
    const int tx = threadIdx.x & 31, ty = threadIdx.x >> 5;   // 8 rows
#pragma unroll
    for (int i = 0; i < 32; i += 8)
        t[ty + i][tx] = W[(size_t)(k0 + ty + i) * N + n0 + tx];
    __syncthreads();
#pragma unroll
    for (int i = 0; i < 32; i += 8)
        Wt[(size_t)(n0 + ty + i) * K + k0 + tx] = (f16)t[tx][ty + i];
}

// ---------------- x fp32 -> fp16 --------------------------------------------
__global__ __launch_bounds__(256) void f2h_k(const float* __restrict__ x,
                                             f16* __restrict__ xh) {
    size_t i = ((size_t)blockIdx.x * 256 + threadIdx.x) * 4;
    float4 v = *(const float4*)&x[i];
    f16x4 s;
    s.x = (f16)v.x; s.y = (f16)v.y; s.z = (f16)v.z; s.w = (f16)v.w;
    *(f16x4*)&xh[i] = s;
}

// ------- a transform: a_c = sigmoid(|a|)*a/|a| (fp16 in place) --------------
__global__ __launch_bounds__(256) void a_transform_k(f16* __restrict__ a2d) {
    int gid = blockIdx.x * 256 + threadIdx.x;   // < M*D
    int j   = gid & 1023;
    int row = gid >> 10;
    size_t i0 = (size_t)row * 2048 + j;
    float ar = (float)a2d[i0], ai = (float)a2d[i0 + 1024];
    float mag = sqrtf(ar * ar + ai * ai);
    float sg  = 1.0f / (1.0f + expf(-mag));
    float re, im;
    if (mag > 1e-30f) { float s = sg / mag; re = ar * s; im = ai * s; }
    else              { re = sg; im = 0.0f; }
    a2d[i0]        = (f16)re;
    a2d[i0 + 1024] = (f16)im;
}

// ---------------- chunked complex scan (fp32 state) -------------------------
__global__ __launch_bounds__(256) void scan_pass1_k(const f16* __restrict__ a2d,
                                                    const f16* __restrict__ kv,
                                                    float4* __restrict__ chunk) {
    int tid = blockIdx.x * 256 + threadIdx.x;    // < CBD
    int d   = tid & 1023;
    int t1  = tid >> 10;
    int b   = t1 & 3;
    int c   = t1 >> 2;
    int t0  = c * CLEN;
    int rbase = b * Ss;
    float Are = 1.0f, Aim = 0.0f, Hre = 0.0f, Him = 0.0f;
    for (int t = t0; t < t0 + CLEN; ++t) {
        int r = rbase + t;
        float are = (float)a2d[(size_t)r * 2048 + d];
        float aim = (float)a2d[(size_t)r * 2048 + 1024 + d];
        float kvv = (float)kv[(size_t)r * 1024 + d];
        float hre = are * Hre - aim * Him + kvv;
        float him = are * Him + aim * Hre;
        Hre = hre; Him = him;
        float pre = are * Are - aim * Aim;
        float pim = are * Aim + aim * Are;
        Are = pre; Aim = pim;
    }
    chunk[tid] = make_float4(Are, Aim, Hre, Him);
}

__global__ __launch_bounds__(256) void scan_pass2_k(const float4* __restrict__ chunk,
                                                    float2* __restrict__ carry,
                                                    float* __restrict__ stats) {
    int tid = blockIdx.x * blockDim.x + threadIdx.x;  // < B*D = 4096
    if (tid < 512) stats[tid] = 0.0f;                 // ws is poisoned: zero gn stats
    float hre = 0.0f, him = 0.0f;
    for (int c = 0; c < CHUNKS; ++c) {
        int task = c * BD + tid;
        float4 ch = chunk[task];
        carry[task] = make_float2(hre, him);
        float nre = ch.x * hre - ch.y * him + ch.z;
        float nim = ch.x * him + ch.y * hre + ch.w;
        hre = nre; him = nim;
    }
}

__global__ __launch_bounds__(256) void scan_pass3_k(const f16* __restrict__ a2d,
                                                    const f16* __restrict__ kv,
                                                    const f16* __restrict__ qb,
                                                    const float2* __restrict__ carry,
                                                    f16* __restrict__ yre,
                                                    float* __restrict__ stats) {
    int tid = blockIdx.x * 256 + threadIdx.x;    // < CBD
    int d   = tid & 1023;
    int t1  = tid >> 10;
    int b   = t1 & 3;
    int c   = t1 >> 2;
    int t0  = c * CLEN;
    int rbase = b * Ss;
    float2 cr = carry[tid];
    float hre = cr.x, him = cr.y;
    float sre = 0.0f, sim = 0.0f, s2 = 0.0f;
    for (int t = t0; t < t0 + CLEN; ++t) {
        int r = rbase + t;
        float are = (float)a2d[(size_t)r * 2048 + d];
        float aim = (float)a2d[(size_t)r * 2048 + 1024 + d];
        float kvv = (float)kv[(size_t)r * 1024 + d];
        float nre = are * hre - aim * him + kvv;
        float nim = are * him + aim * hre;
        hre = nre; him = nim;
        float qv  = (float)qb[(size_t)r * 1024 + d];
        float yr_ = qv * hre;
        float yi_ = qv * him;
        yre[(size_t)r * 1024 + d] = (f16)yr_;
        sre += yr_; sim += yi_; s2 += yr_ * yr_ + yi_ * yi_;
    }
#pragma unroll
    for (int off = 16; off > 0; off >>= 1) {
        sre += __shfl_down(sre, off, 32);
        sim += __shfl_down(sim, off, 32);
        s2  += __shfl_down(s2,  off, 32);
    }
    if ((threadIdx.x & 31) == 0) {
        int idx = (b * 32 + (d >> 5)) * 4;
        atomicAdd(&stats[idx + 0], sre);
        atomicAdd(&stats[idx + 1], sim);
        atomicAdd(&stats[idx + 2], s2);
    }
}

// ---------------- groupnorm (real part) + silu-gate, fp16 in place ----------
__global__ __launch_bounds__(256) void gn_gate_k(f16* __restrict__ y,
                                                 const f16* __restrict__ g,
                                                 const float* __restrict__ stats,
                                                 const float* __restrict__ gn_scale,
                                                 const float* __restrict__ gn_bias) {
    size_t gid = (size_t)blockIdx.x * 256 + threadIdx.x;  // < M*D
    int d   = (int)(gid & 1023);
    int row = (int)(gid >> 10);
    int b   = row >> 12;
    int grp = d >> 5;
    const float* st = &stats[(b * 32 + grp) * 4];
    const float invN = 1.0f / 131072.0f;       // S * (D/G)
    float mre = st[0] * invN;
    float mim = st[1] * invN;
    float var = st[2] * invN - mre * mre - mim * mim;
    float rstd = rsqrtf(var + EPSN);
    float re = ((float)y[gid] - mre) * rstd * gn_scale[d] + gn_bias[d];
    y[gid] = (f16)(re * (float)g[gid]);
}

// ---------------- layernorm over D=1024: out = LN(a + b) --------------------
__device__ __forceinline__ float ldf(const float* p, size_t i) { return p[i]; }
__device__ __forceinline__ float ldf(const f16* p, size_t i)   { return (float)p[i]; }
__device__ __forceinline__ void  stf(float* p, size_t i, float v) { p[i] = v; }
__device__ __forceinline__ void  stf(f16* p, size_t i, float v)   { p[i] = (f16)v; }

__device__ __forceinline__ float block_reduce_sum(float v, float* s4, int tid) {
#pragma unroll
    for (int off = 32; off > 0; off >>= 1) v += __shfl_down(v, off, 64);
    __syncthreads();
    if ((tid & 63) == 0) s4[tid >> 6] = v;
    __syncthreads();
    return s4[0] + s4[1] + s4[2] + s4[3];
}

template <typename TA, typename TB, typename TO>
__global__ __launch_bounds__(256) void ln_k(const TA* __restrict__ a,
                                            const TB* __restrict__ b,
                                            const float* __restrict__ scale,
                                            const float* __restrict__ bias,
                                            TO* __restrict__ out) {
    __shared__ float s4[4];
    int row = blockIdx.x;
    size_t base = (size_t)row * 1024;
    int tid = threadIdx.x;
    float v[4];
    float s = 0.0f;
#pragma unroll
    for (int i = 0; i < 4; ++i) {
        int d = tid + i * 256;
        v[i] = ldf(a, base + d) + ldf(b, base + d);
        s += v[i];
    }
    float mu = block_reduce_sum(s, s4, tid) * (1.0f / 1024.0f);
    float s2 = 0.0f;
#pragma unroll
    for (int i = 0; i < 4; ++i) {
        float dv = v[i] - mu;
        s2 += dv * dv;
    }
    float var = block_reduce_sum(s2, s4, tid) * (1.0f / 1024.0f);
    float rstd = rsqrtf(var + EPSN);
#pragma unroll
    for (int i = 0; i < 4; ++i) {
        int d = tid + i * 256;
        stf(out, base + d, (v[i] - mu) * rstd * scale[d] + bias[d]);
    }
}

// ---------------------------------------------------------------------------
extern "C" void kernel_launch(void* const* d_in, const int* in_sizes, int n_in,
                              void* d_out, int out_size, void* d_ws, size_t ws_size,
                              hipStream_t stream) {
    const float* x        = (const float*)d_in[0];
    const float* Wq       = (const float*)d_in[1];
    const float* Wk       = (const float*)d_in[2];
    const float* Wv       = (const float*)d_in[3];
    const float* Wa       = (const float*)d_in[4];
    const float* Wg       = (const float*)d_in[5];
    const float* Wo       = (const float*)d_in[6];
    const float* gn_scale = (const float*)d_in[7];
    const float* gn_bias  = (const float*)d_in[8];
    const float* ln1_s    = (const float*)d_in[9];
    const float* ln1_b    = (const float*)d_in[10];
    const float* W1       = (const float*)d_in[11];
    const float* b1       = (const float*)d_in[12];
    const float* W2       = (const float*)d_in[13];
    const float* b2       = (const float*)d_in[14];
    const float* ln2_s    = (const float*)d_in[15];
    const float* ln2_b    = (const float*)d_in[16];
    float* out = (float*)d_out;

    char* base = (char*)d_ws;
    f16* W1T = (f16*)(base + 0 * MiB);    // [4096, 1024]
    f16* W2T = (f16*)(base + 8 * MiB);    // [1024, 4096]
    f16* WqT = (f16*)(base + 16 * MiB);   // [1024, 1024]
    f16* WkT = (f16*)(base + 18 * MiB);
    f16* WvT = (f16*)(base + 20 * MiB);
    f16* WgT = (f16*)(base + 22 * MiB);
    f16* WoT = (f16*)(base + 24 * MiB);
    f16* WaT = (f16*)(base + 26 * MiB);   // [2048, 1024]
    float4* chunk = (float4*)(base + 30 * MiB);
    float2* carry = (float2*)(base + 34 * MiB);
    float*  stats = (float*)(base + 36 * MiB);
    f16* xb  = (f16*)(base + 37 * MiB);
    f16* kvb = (f16*)(base + 69 * MiB);
    f16* qb  = (f16*)(base + 101 * MiB);
    f16* gb  = (f16*)(base + 133 * MiB);
    f16* yb  = (f16*)(base + 165 * MiB);  // ends 197 MiB
    // aliases (lifetimes verified):
    f16*   ab = (f16*)d_out;              // [M,2D] fp16 = 64 MiB; dead after pass3
    f16*   yo = qb;                       // Wo out; q dead after pass3
    f16*   x1 = xb;                       // post-ln1; xb dead after projections
    f16*   h1 = kvb;                      // [M,F] f16 = 128 MiB: 69..197 all dead
    float* h2 = (float*)d_out;            // fp32 [M,D]; a dead after pass3

    dim3 blk(256);

    // 0. conversions
    f2h_k<<<Mrows, blk, 0, stream>>>(x, xb);
    wtrans_k<<<dim3(128, 32), blk, 0, stream>>>(W1, W1T, Dd, Ff);
    wtrans_k<<<dim3(32, 128), blk, 0, stream>>>(W2, W2T, Ff, Dd);
    wtrans_k<<<dim3(32, 32),  blk, 0, stream>>>(Wq, WqT, Dd, Dd);
    wtrans_k<<<dim3(32, 32),  blk, 0, stream>>>(Wk, WkT, Dd, Dd);
    wtrans_k<<<dim3(32, 32),  blk, 0, stream>>>(Wv, WvT, Dd, Dd);
    wtrans_k<<<dim3(32, 32),  blk, 0, stream>>>(Wg, WgT, Dd, Dd);
    wtrans_k<<<dim3(32, 32),  blk, 0, stream>>>(Wo, WoT, Dd, Dd);
    wtrans_k<<<dim3(64, 32),  blk, 0, stream>>>(Wa, WaT, Dd, 2 * Dd);

    // 1. input projections
    mgemm_k<0, f16><<<dim3(Dd / 128, Mrows / 128), blk, 0, stream>>>(xb, WqT, qb, Mrows, Dd, Dd, nullptr);
    mgemm_k<0, f16><<<dim3(Dd / 128, Mrows / 128), blk, 0, stream>>>(xb, WkT, kvb, Mrows, Dd, Dd, nullptr);
    mgemm_k<3, f16><<<dim3(Dd / 128, Mrows / 128), blk, 0, stream>>>(xb, WvT, kvb, Mrows, Dd, Dd, nullptr);
    mgemm_k<0, f16><<<dim3(2 * Dd / 128, Mrows / 128), blk, 0, stream>>>(xb, WaT, ab, Mrows, 2 * Dd, Dd, nullptr);
    mgemm_k<4, f16><<<dim3(Dd / 128, Mrows / 128), blk, 0, stream>>>(xb, WgT, gb, Mrows, Dd, Dd, nullptr);

    // 2. a transform (fp16, in place in d_out)
    a_transform_k<<<MD / 256, blk, 0, stream>>>(ab);

    // 3. chunked scan
    scan_pass1_k<<<CBD / 256, blk, 0, stream>>>(ab, kvb, chunk);
    scan_pass2_k<<<BD / 256, blk, 0, stream>>>(chunk, carry, stats);
    scan_pass3_k<<<CBD / 256, blk, 0, stream>>>(ab, kvb, qb, carry, yb, stats);

    // 4. groupnorm + gate (in place on yb)
    gn_gate_k<<<MD / 256, blk, 0, stream>>>(yb, gb, stats, gn_scale, gn_bias);

    // 5. output projection + ln1 (x1 -> xb slot; xb dead after projections)
    mgemm_k<0, f16><<<dim3(Dd / 128, Mrows / 128), blk, 0, stream>>>(yb, WoT, yo, Mrows, Dd, Dd, nullptr);
    ln_k<float, f16, f16><<<Mrows, blk, 0, stream>>>(x, yo, ln1_s, ln1_b, x1);

    // 6. MLP (h1 overlays 69..197 MiB; h2 -> d_out fp32)
    mgemm_k<1, f16  ><<<dim3(Ff / 128, Mrows / 128), blk, 0, stream>>>(x1, W1T, h1, Mrows, Ff, Dd, b1);
    mgemm_k<2, float><<<dim3(Dd / 128, Mrows / 128), blk, 0, stream>>>(h1, W2T, h2, Mrows, Dd, Ff, b2);

    // 7. final layernorm -> out (in place over h2: per-thread read-then-write)
    ln_k<f16, float, float><<<Mrows, blk, 0, stream>>>(x1, h2, ln2_s, ln2_b, out);
}

// Round 2
// 1045.824 us; speedup vs baseline: 1.2226x; 1.0710x over previous
//
#include <hip/hip_runtime.h>
#include <cstdint>
#include <cstddef>

// ---------------------------------------------------------------------------
// GateLoop block, round 7:
//   (a) fast gelu/sigmoid: libm tanhf in the W1 epilogue was ~half the W1
//       kernel (VALUBusy 67%). exp2+rcp form (~10 VALU ops, clamped).
//   (b) projection consolidation: q|k|v|g as ONE N=4096 GEMM into P[M,4096]
//       (stacked [WqT;WkT;WvT;WgT]); a separate N=2048. v*k moves into the
//       scan inner loop (fp32 product of two f16s -- drops an intermediate
//       f16 rounding); silu(g) moves into gn_gate (memory-bound).
//       5 GEMM launches -> 2; A fetched 2x not 5x.
//   (c) f16x8-vectorized gn_gate / a_transform (G13).
//   Carried from r6: XCD-chunked swizzle, double-buffered single-barrier
//   K-loop, LDS chunk-XOR swizzle (bank conflicts = 0).
//
// Pipeline:
//   0. x -> fp16; weights -> transposed fp16 [N,K] (qkvg stacked)
//   1. mgemm x@[Wq|Wk|Wv|Wg] -> P[M,4096]; x@Wa -> ab (d_out)
//   2. a_transform in place (fp16, d_out)
//   3. chunked scan (3 passes, fp32 state); k*v computed inline;
//      pass3 writes y in-place over P's q columns (per-elem read-then-write)
//   4. gn_gate + silu(g) (vectorized, in place on y cols of P)
//   5. mgemm y@Wo -> yo (d_out, a dead); ln1 -> x1 (xb slot)
//   6. mgemm x1@W1(+b1,fast gelu) -> h1 (overlays P); h1@W2(+b2) -> h2 (d_out)
//   7. ln2(x1 + h2) -> out (in place over h2)
//
// ws layout (MiB): 0 W1T(8) | 8 W2T(8) | 16 PWT=[Wq|Wk|Wv|Wg]T(8) |
//   24 WoT(2) | 26 WaT(4) | 30 chunk(4) | 34 carry(2) | 36 stats |
//   37 xb(32) | 69 P(128) | 197 end.  (197 MiB proven safe r2)
// Aliases: ab & yo & h2 -> d_out; y over P q-cols; h1 -> P; x1 -> xb.
// ---------------------------------------------------------------------------

#define EPSN 1e-6f

typedef _Float16 f16;
typedef _Float16 f16x8 __attribute__((ext_vector_type(8)));
typedef _Float16 f16x4 __attribute__((ext_vector_type(4)));
typedef float    f32x4 __attribute__((ext_vector_type(4)));

static constexpr int    Bb     = 4;
static constexpr int    Ss     = 4096;
static constexpr int    Dd     = 1024;
static constexpr int    Ff     = 4096;
static constexpr int    Mrows  = Bb * Ss;                  // 16384
static constexpr size_t MD     = (size_t)Mrows * Dd;       // 16777216
static constexpr int    CHUNKS = 64;
static constexpr int    CLEN   = Ss / CHUNKS;              // 64
static constexpr int    BD     = Bb * Dd;                  // 4096
static constexpr int    CBD    = CHUNKS * BD;              // 262144
static constexpr size_t MiB    = 1024 * 1024;
static constexpr int    PLD    = 4096;                     // P row stride

__device__ __forceinline__ float fast_sigmoid(float x) {
    float e = __builtin_amdgcn_exp2f(-1.4426950408889634f * x);
    return __builtin_amdgcn_rcpf(1.0f + e);
}
__device__ __forceinline__ float gelu_tanh(float x) {
    float z = 0.7978845608028654f * (x + 0.044715f * x * x * x);
    z = fminf(fmaxf(z, -10.0f), 10.0f);          // tanh(+-10)=+-1 to fp32
    float e = __builtin_amdgcn_exp2f(2.885390081777927f * z);   // e^{2z}
    float t = (e - 1.0f) * __builtin_amdgcn_rcpf(e + 1.0f);
    return 0.5f * x * (1.0f + t);
}

// async global->LDS, 16 B per lane; lds dest = base + lane*16 (wave-uniform base)
__device__ __forceinline__ void async16(const void* g, void* l) {
    __builtin_amdgcn_global_load_lds(
        (const __attribute__((address_space(1))) unsigned int*)(uintptr_t)g,
        (__attribute__((address_space(3))) unsigned int*)(uintptr_t)l,
        16, 0, 0);
}

// ------- MFMA GEMM: C[M,N](ldc) = A[M,K](lda,f16) @ Bt[N,K](f16)^T ----------
// EPI: 0 none | 1 bias+gelu | 2 bias
template <int EPI, typename TC>
__global__ __launch_bounds__(256) void mgemm_k(const f16* __restrict__ A, int lda,
                                               const f16* __restrict__ Bt,
                                               TC* __restrict__ C, int ldc,
                                               int M, int N, int K,
                                               const float* __restrict__ bias) {
    __shared__ f16 As[2][128 * 32];
    __shared__ f16 Bs[2][128 * 32];
    const int tid  = threadIdx.x;
    const int wave = tid >> 6;
    const int lane = tid & 63;

    // XCD-chunked bijective swizzle (all grids have nwg % 8 == 0)
    const int gx  = gridDim.x;
    const int nwg = gx * gridDim.y;
    int bid = blockIdx.y * gx + blockIdx.x;
    bid = (bid & 7) * (nwg >> 3) + (bid >> 3);
    const int bm = (bid / gx) * 128;
    const int bn = (bid % gx) * 128;

    const int rw = (wave & 1) * 64;
    const int cw = (wave >> 1) * 64;

    // staging: lane l owns LDS (row = l>>2, chunk = l&3); fetch global chunk
    // c = (l&3) ^ ((row>>1)&3) = (l&3) ^ ((l>>3)&3)
    const int swzc = (((lane & 3) ^ (lane >> 3)) & 3) * 8;
    const f16* gA = A  + (size_t)(bm + wave * 32 + (lane >> 2)) * lda + swzc;
    const f16* gB = Bt + (size_t)(bn + wave * 32 + (lane >> 2)) * K   + swzc;
    f16* const lA0 = &As[0][wave * 1024];
    f16* const lA1 = &As[1][wave * 1024];
    f16* const lB0 = &Bs[0][wave * 1024];
    f16* const lB1 = &Bs[1][wave * 1024];

    f32x4 acc[4][4] = {};

    // fragment read: want global chunk g=(lane>>4) at row (..+fr);
    // stored at LDS chunk g ^ ((fr>>1)&3)
    const int fr  = lane & 15;
    const int fco = (((lane >> 4) ^ (lane >> 1)) & 3) * 8;

#define MG_STAGE(KOFF, LA, LB)                                         \
    {                                                                  \
        async16(gA + (KOFF),                     (LA));                \
        async16(gA + 16 * (size_t)lda + (KOFF),  (LA) + 512);          \
        async16(gB + (KOFF),                     (LB));                \
        async16(gB + 16 * (size_t)K + (KOFF),    (LB) + 512);          \
    }

#define MG_COMPUTE(LSA, LSB)                                                   \
    {                                                                          \
        f16x8 af[4], bfr[4];                                                   \
        _Pragma("unroll") for (int i = 0; i < 4; ++i)                          \
            af[i] = *(const f16x8*)&(LSA)[(rw + i * 16 + fr) * 32 + fco];      \
        _Pragma("unroll") for (int j = 0; j < 4; ++j)                          \
            bfr[j] = *(const f16x8*)&(LSB)[(cw + j * 16 + fr) * 32 + fco];     \
        _Pragma("unroll") for (int i = 0; i < 4; ++i)                          \
            _Pragma("unroll") for (int j = 0; j < 4; ++j)                      \
                acc[i][j] = __builtin_amdgcn_mfma_f32_16x16x32_f16(            \
                    af[i], bfr[j], acc[i][j], 0, 0, 0);                        \
    }

    MG_STAGE(0, lA0, lB0);
    for (int k0 = 0; k0 < K; k0 += 64) {
        __syncthreads();
        MG_STAGE(k0 + 32, lA1, lB1);
        MG_COMPUTE(As[0], Bs[0]);
        __syncthreads();
        if (k0 + 64 < K) MG_STAGE(k0 + 64, lA0, lB0);
        MG_COMPUTE(As[1], Bs[1]);
    }
#undef MG_STAGE
#undef MG_COMPUTE

    // epilogue: C row = (lane>>4)*4 + reg, col = lane&15  (dtype-independent)
    const int er = (lane >> 4) * 4;
    const int ec = lane & 15;
#pragma unroll
    for (int i = 0; i < 4; ++i) {
#pragma unroll
        for (int j = 0; j < 4; ++j) {
            const int col = bn + cw + j * 16 + ec;
#pragma unroll
            for (int r = 0; r < 4; ++r) {
                const size_t row = (size_t)(bm + rw + i * 16 + er + r);
                float o = acc[i][j][r];
                if (EPI == 1 || EPI == 2) o += bias[col];
                if (EPI == 1) o = gelu_tanh(o);
                if (sizeof(TC) == 4) ((float*)C)[row * ldc + col] = o;
                else                 ((f16*)C)[row * ldc + col] = (f16)o;
            }
        }
    }
}

// ---------------- weight transpose+convert: Wt[n][k] = f16(W[k][n]) ---------
__global__ __launch_bounds__(256) void wtrans_k(const float* __restrict__ W,
                                                f16* __restrict__ Wt,
                                                int K, int N) {
    __shared__ float t[32][33];
    const int n0 = blockIdx.x * 32, k0 = blockIdx.y * 32;
    const int tx = threadIdx.x & 31, ty = threadIdx.x >> 5;   // 8 rows
#pragma unroll
    for (int i = 0; i < 32; i += 8)
        t[ty + i][tx] = W[(size_t)(k0 + ty + i) * N + n0 + tx];
    __syncthreads();
#pragma unroll
    for (int i = 0; i < 32; i += 8)
        Wt[(size_t)(n0 + ty + i) * K + k0 + tx] = (f16)t[tx][ty + i];
}

// ---------------- x fp32 -> fp16 --------------------------------------------
__global__ __launch_bounds__(256) void f2h_k(const float* __restrict__ x,
                                             f16* __restrict__ xh) {
    size_t i = ((size_t)blockIdx.x * 256 + threadIdx.x) * 4;
    float4 v = *(const float4*)&x[i];
    f16x4 s;
    s.x = (f16)v.x; s.y = (f16)v.y; s.z = (f16)v.z; s.w = (f16)v.w;
    *(f16x4*)&xh[i] = s;
}

// ------- a transform: a_c = sigmoid(|a|)*a/|a| (fp16 in place, x8) ----------
__global__ __launch_bounds__(256) void a_transform_k(f16* __restrict__ a2d) {
    size_t gid = (size_t)blockIdx.x * 256 + threadIdx.x;   // < M*D/8
    int    j8  = (int)(gid & 127) * 8;
    size_t row = gid >> 7;
    f16x8 vr = *(f16x8*)&a2d[row * 2048 + j8];
    f16x8 vi = *(f16x8*)&a2d[row * 2048 + 1024 + j8];
#pragma unroll
    for (int i = 0; i < 8; ++i) {
        float ar = (float)vr[i], ai = (float)vi[i];
        float mag = sqrtf(ar * ar + ai * ai);
        float sg  = fast_sigmoid(mag);
        float re, im;
        if (mag > 1e-30f) { float s = sg * __builtin_amdgcn_rcpf(mag); re = ar * s; im = ai * s; }
        else              { re = sg; im = 0.0f; }
        vr[i] = (f16)re; vi[i] = (f16)im;
    }
    *(f16x8*)&a2d[row * 2048 + j8]        = vr;
    *(f16x8*)&a2d[row * 2048 + 1024 + j8] = vi;
}

// ---------------- chunked complex scan (fp32 state) -------------------------
// P columns: q 0..1023 | k 1024..2047 | v 2048..3071 | g 3072..4095
__global__ __launch_bounds__(256) void scan_pass1_k(const f16* __restrict__ a2d,
                                                    const f16* __restrict__ P,
                                                    float4* __restrict__ chunk) {
    int tid = blockIdx.x * 256 + threadIdx.x;    // < CBD
    int d   = tid & 1023;
    int t1  = tid >> 10;
    int b   = t1 & 3;
    int c   = t1 >> 2;
    int t0  = c * CLEN;
    int rbase = b * Ss;
    float Are = 1.0f, Aim = 0.0f, Hre = 0.0f, Him = 0.0f;
    for (int t = t0; t < t0 + CLEN; ++t) {
        int r = rbase + t;
        float are = (float)a2d[(size_t)r * 2048 + d];
        float aim = (float)a2d[(size_t)r * 2048 + 1024 + d];
        float kvv = (float)P[(size_t)r * PLD + 1024 + d]
                  * (float)P[(size_t)r * PLD + 2048 + d];
        float hre = are * Hre - aim * Him + kvv;
        float him = are * Him + aim * Hre;
        Hre = hre; Him = him;
        float pre = are * Are - aim * Aim;
        float pim = are * Aim + aim * Are;
        Are = pre; Aim = pim;
    }
    chunk[tid] = make_float4(Are, Aim, Hre, Him);
}

__global__ __launch_bounds__(256) void scan_pass2_k(const float4* __restrict__ chunk,
                                                    float2* __restrict__ carry,
                                                    float* __restrict__ stats) {
    int tid = blockIdx.x * blockDim.x + threadIdx.x;  // < B*D = 4096
    if (tid < 512) stats[tid] = 0.0f;                 // ws is poisoned: zero gn stats
    float hre = 0.0f, him = 0.0f;
    for (int c = 0; c < CHUNKS; ++c) {
        int task = c * BD + tid;
        float4 ch = chunk[task];
        carry[task] = make_float2(hre, him);
        float nre = ch.x * hre - ch.y * him + ch.z;
        float nim = ch.x * him + ch.y * hre + ch.w;
        hre = nre; him = nim;
    }
}

// pass3: y written in place over P's q columns (per-elem read-then-write)
__global__ __launch_bounds__(256) void scan_pass3_k(const f16* __restrict__ a2d,
                                                    f16* __restrict__ P,
                                                    const float2* __restrict__ carry,
                                                    float* __restrict__ stats) {
    int tid = blockIdx.x * 256 + threadIdx.x;    // < CBD
    int d   = tid & 1023;
    int t1  = tid >> 10;
    int b   = t1 & 3;
    int c   = t1 >> 2;
    int t0  = c * CLEN;
    int rbase = b * Ss;
    float2 cr = carry[tid];
    float hre = cr.x, him = cr.y;
    float sre = 0.0f, sim = 0.0f, s2 = 0.0f;
    for (int t = t0; t < t0 + CLEN; ++t) {
        int r = rbase + t;
        float are = (float)a2d[(size_t)r * 2048 + d];
        float aim = (float)a2d[(size_t)r * 2048 + 1024 + d];
        float kvv = (float)P[(size_t)r * PLD + 1024 + d]
                  * (float)P[(size_t)r * PLD + 2048 + d];
        float nre = are * hre - aim * him + kvv;
        float nim = are * him + aim * hre;
        hre = nre; him = nim;
        float qv  = (float)P[(size_t)r * PLD + d];
        float yr_ = qv * hre;
        float yi_ = qv * him;
        P[(size_t)r * PLD + d] = (f16)yr_;       // overwrite q with y (safe)
        sre += yr_; sim += yi_; s2 += yr_ * yr_ + yi_ * yi_;
    }
#pragma unroll
    for (int off = 16; off > 0; off >>= 1) {
        sre += __shfl_down(sre, off, 32);
        sim += __shfl_down(sim, off, 32);
        s2  += __shfl_down(s2,  off, 32);
    }
    if ((threadIdx.x & 31) == 0) {
        int idx = (b * 32 + (d >> 5)) * 4;
        atomicAdd(&stats[idx + 0], sre);
        atomicAdd(&stats[idx + 1], sim);
        atomicAdd(&stats[idx + 2], s2);
    }
}

// ------- groupnorm (real) + silu(g)-gate, f16x8, in place on y cols ---------
__global__ __launch_bounds__(256) void gn_gate_k(f16* __restrict__ P,
                                                 const float* __restrict__ stats,
                                                 const float* __restrict__ gn_scale,
                                                 const float* __restrict__ gn_bias) {
    size_t gid = (size_t)blockIdx.x * 256 + threadIdx.x;  // < M*D/8
    int d8  = (int)(gid & 127) * 8;
    int row = (int)(gid >> 7);
    int b   = row >> 12;
    int grp = d8 >> 5;
    const float* st = &stats[(b * 32 + grp) * 4];
    const float invN = 1.0f / 131072.0f;       // S * (D/G)
    float mre = st[0] * invN;
    float mim = st[1] * invN;
    float var = st[2] * invN - mre * mre - mim * mim;
    float rstd = rsqrtf(var + EPSN);
    f16x8 yv = *(f16x8*)&P[(size_t)row * PLD + d8];
    f16x8 gv = *(const f16x8*)&P[(size_t)row * PLD + 3072 + d8];
#pragma unroll
    for (int i = 0; i < 8; ++i) {
        float re = ((float)yv[i] - mre) * rstd * gn_scale[d8 + i] + gn_bias[d8 + i];
        float gx = (float)gv[i];
        yv[i] = (f16)(re * gx * fast_sigmoid(gx));
    }
    *(f16x8*)&P[(size_t)row * PLD + d8] = yv;
}

// ---------------- layernorm over D=1024: out = LN(a + b) --------------------
__device__ __forceinline__ float ldf(const float* p, size_t i) { return p[i]; }
__device__ __forceinline__ float ldf(const f16* p, size_t i)   { return (float)p[i]; }
__device__ __forceinline__ void  stf(float* p, size_t i, float v) { p[i] = v; }
__device__ __forceinline__ void  stf(f16* p, size_t i, float v)   { p[i] = (f16)v; }

__device__ __forceinline__ float block_reduce_sum(float v, float* s4, int tid) {
#pragma unroll
    for (int off = 32; off > 0; off >>= 1) v += __shfl_down(v, off, 64);
    __syncthreads();
    if ((tid & 63) == 0) s4[tid >> 6] = v;
    __syncthreads();
    return s4[0] + s4[1] + s4[2] + s4[3];
}

template <typename TA, typename TB, typename TO>
__global__ __launch_bounds__(256) void ln_k(const TA* __restrict__ a,
                                            const TB* __restrict__ b,
                                            const float* __restrict__ scale,
                                            const float* __restrict__ bias,
                                            TO* __restrict__ out) {
    __shared__ float s4[4];
    int row = blockIdx.x;
    size_t base = (size_t)row * 1024;
    int tid = threadIdx.x;
    float v[4];
    float s = 0.0f;
#pragma unroll
    for (int i = 0; i < 4; ++i) {
        int d = tid + i * 256;
        v[i] = ldf(a, base + d) + ldf(b, base + d);
        s += v[i];
    }
    float mu = block_reduce_sum(s, s4, tid) * (1.0f / 1024.0f);
    float s2 = 0.0f;
#pragma unroll
    for (int i = 0; i < 4; ++i) {
        float dv = v[i] - mu;
        s2 += dv * dv;
    }
    float var = block_reduce_sum(s2, s4, tid) * (1.0f / 1024.0f);
    float rstd = rsqrtf(var + EPSN);
#pragma unroll
    for (int i = 0; i < 4; ++i) {
        int d = tid + i * 256;
        stf(out, base + d, (v[i] - mu) * rstd * scale[d] + bias[d]);
    }
}

// ---------------------------------------------------------------------------
extern "C" void kernel_launch(void* const* d_in, const int* in_sizes, int n_in,
                              void* d_out, int out_size, void* d_ws, size_t ws_size,
                              hipStream_t stream) {
    const float* x        = (const float*)d_in[0];
    const float* Wq       = (const float*)d_in[1];
    const float* Wk       = (const float*)d_in[2];
    const float* Wv       = (const float*)d_in[3];
    const float* Wa       = (const float*)d_in[4];
    const float* Wg       = (const float*)d_in[5];
    const float* Wo       = (const float*)d_in[6];
    const float* gn_scale = (const float*)d_in[7];
    const float* gn_bias  = (const float*)d_in[8];
    const float* ln1_s    = (const float*)d_in[9];
    const float* ln1_b    = (const float*)d_in[10];
    const float* W1       = (const float*)d_in[11];
    const float* b1       = (const float*)d_in[12];
    const float* W2       = (const float*)d_in[13];
    const float* b2       = (const float*)d_in[14];
    const float* ln2_s    = (const float*)d_in[15];
    const float* ln2_b    = (const float*)d_in[16];
    float* out = (float*)d_out;

    char* base = (char*)d_ws;
    f16* W1T = (f16*)(base + 0 * MiB);    // [4096, 1024]
    f16* W2T = (f16*)(base + 8 * MiB);    // [1024, 4096]
    f16* PWT = (f16*)(base + 16 * MiB);   // [4096, 1024] = [Wq|Wk|Wv|Wg]^T
    f16* WoT = (f16*)(base + 24 * MiB);   // [1024, 1024]
    f16* WaT = (f16*)(base + 26 * MiB);   // [2048, 1024]
    float4* chunk = (float4*)(base + 30 * MiB);
    float2* carry = (float2*)(base + 34 * MiB);
    float*  stats = (float*)(base + 36 * MiB);
    f16* xb  = (f16*)(base + 37 * MiB);   // [M,1024] fp16 = 32 MiB
    f16* P   = (f16*)(base + 69 * MiB);   // [M,4096] fp16 = 128 MiB, ends 197
    // aliases (lifetimes verified):
    f16*   ab = (f16*)d_out;              // [M,2048] fp16 = 64 MiB; dead after pass3
    f16*   yo = (f16*)d_out;              // Wo out [M,1024] f16; a dead by then
    f16*   x1 = xb;                       // post-ln1; xb dead after projections
    f16*   h1 = P;                        // [M,F] f16 = 128 MiB; P dead after Wo
    float* h2 = (float*)d_out;            // fp32 [M,D]; yo dead after ln1

    dim3 blk(256);

    // 0. conversions (PWT rows: 0 q | 1024 k | 2048 v | 3072 g)
    f2h_k<<<Mrows, blk, 0, stream>>>(x, xb);
    wtrans_k<<<dim3(128, 32), blk, 0, stream>>>(W1, W1T, Dd, Ff);
    wtrans_k<<<dim3(32, 128), blk, 0, stream>>>(W2, W2T, Ff, Dd);
    wtrans_k<<<dim3(32, 32),  blk, 0, stream>>>(Wq, PWT + 0u * 1048576, Dd, Dd);
    wtrans_k<<<dim3(32, 32),  blk, 0, stream>>>(Wk, PWT + 1u * 1048576, Dd, Dd);
    wtrans_k<<<dim3(32, 32),  blk, 0, stream>>>(Wv, PWT + 2u * 1048576, Dd, Dd);
    wtrans_k<<<dim3(32, 32),  blk, 0, stream>>>(Wg, PWT + 3u * 1048576, Dd, Dd);
    wtrans_k<<<dim3(32, 32),  blk, 0, stream>>>(Wo, WoT, Dd, Dd);
    wtrans_k<<<dim3(64, 32),  blk, 0, stream>>>(Wa, WaT, Dd, 2 * Dd);

    // 1. projections: one N=4096 GEMM (q|k|v|g) + one N=2048 (a)
    mgemm_k<0, f16><<<dim3(32, 128), blk, 0, stream>>>(xb, Dd, PWT, P, PLD, Mrows, 4096, Dd, nullptr);
    mgemm_k<0, f16><<<dim3(16, 128), blk, 0, stream>>>(xb, Dd, WaT, ab, 2048, Mrows, 2048, Dd, nullptr);

    // 2. a transform (fp16, in place in d_out)
    a_transform_k<<<MD / (256 * 8), blk, 0, stream>>>(ab);

    // 3. chunked scan (k*v inline; y in-place over q cols of P)
    scan_pass1_k<<<CBD / 256, blk, 0, stream>>>(ab, P, chunk);
    scan_pass2_k<<<BD / 256, blk, 0, stream>>>(chunk, carry, stats);
    scan_pass3_k<<<CBD / 256, blk, 0, stream>>>(ab, P, carry, stats);

    // 4. groupnorm + silu(g) gate (in place on y cols of P)
    gn_gate_k<<<MD / (256 * 8), blk, 0, stream>>>(P, stats, gn_scale, gn_bias);

    // 5. output projection (A = y cols of P, lda=PLD) + ln1
    mgemm_k<0, f16><<<dim3(8, 128), blk, 0, stream>>>(P, PLD, WoT, yo, Dd, Mrows, Dd, Dd, nullptr);
    ln_k<float, f16, f16><<<Mrows, blk, 0, stream>>>(x, yo, ln1_s, ln1_b, x1);

    // 6. MLP (h1 overlays P; h2 -> d_out fp32)
    mgemm_k<1, f16  ><<<dim3(32, 128), blk, 0, stream>>>(x1, Dd, W1T, h1, Ff, Mrows, Ff, Dd, b1);
    mgemm_k<2, float><<<dim3(8, 128),  blk, 0, stream>>>(h1, Ff, W2T, h2, Dd, Mrows, Dd, Ff, b2);

    // 7. final layernorm -> out (in place over h2: per-thread read-then-write)
    ln_k<f16, float, float><<<Mrows, blk, 0, stream>>>(x1, h2, ln2_s, ln2_b, out);
}